// Round 16
// baseline (203.971 us; speedup 1.0000x reference)
//
#include <hip/hip_runtime.h>
#include <hip/hip_bf16.h>

typedef short short8 __attribute__((ext_vector_type(8)));
typedef float f32x16 __attribute__((ext_vector_type(16)));

#define M_TOT 16384   // B*S = 4*4096
#define NDIM  1024    // D = U = 1024
#define BK 32
#define NT (NDIM / BK)   // 32 K-tiles

static __device__ __forceinline__ unsigned short f2bf(float f) {
  unsigned int u = __builtin_bit_cast(unsigned int, f);
  unsigned int r = (u + 0x7fffu + ((u >> 16) & 1u)) >> 16;   // RN-even
  return (unsigned short)r;
}
static __device__ __forceinline__ float bf2f(unsigned short u) {
  return __builtin_bit_cast(float, ((unsigned int)u) << 16);
}

// compile-time-only reorder fence (zero runtime cost)
#define CLB() asm volatile("" ::: "memory")
#define VMW(N) asm volatile("s_waitcnt vmcnt(" #N ")" ::: "memory")
#define BAR() do { CLB(); __builtin_amdgcn_s_barrier(); CLB(); } while (0)

// ---------------- cast inputs fp32 -> bf16, vectorized ----------------
__global__ __launch_bounds__(256) void cast_in(const float* __restrict__ in,
                                               unsigned short* __restrict__ out,
                                               int n4) {
  int i = blockIdx.x * 256 + threadIdx.x;
  if (i >= n4) return;
  float4 v = reinterpret_cast<const float4*>(in)[i];
  ushort4 o;
  o.x = f2bf(v.x); o.y = f2bf(v.y); o.z = f2bf(v.z); o.w = f2bf(v.w);
  reinterpret_cast<ushort4*>(out)[i] = o;
}

// ---- transpose-cast 4 weights fp32 [K][N] -> bf16 [N][K], one launch ----
__global__ __launch_bounds__(256) void tcast4(
    const float* __restrict__ w1, const float* __restrict__ w2,
    const float* __restrict__ wg, const float* __restrict__ ws,
    unsigned short* __restrict__ W1t, unsigned short* __restrict__ W2t,
    unsigned short* __restrict__ Wgt, unsigned short* __restrict__ Wst) {
  const int z = blockIdx.z;
  const float* src = (z == 0) ? w1 : (z == 1) ? w2 : (z == 2) ? wg : ws;
  unsigned short* dst = (z == 0) ? W1t : (z == 1) ? W2t : (z == 2) ? Wgt : Wst;
  __shared__ unsigned short tile[32][33];
  int bx = blockIdx.x * 32, by = blockIdx.y * 32;
  int x = threadIdx.x & 31, y = threadIdx.x >> 5;  // 32 x 8
#pragma unroll
  for (int i = 0; i < 32; i += 8)
    tile[y + i][x] = f2bf(src[(size_t)(by + y + i) * NDIM + bx + x]);
  __syncthreads();
#pragma unroll
  for (int i = 0; i < 32; i += 8)
    dst[(size_t)(bx + y + i) * NDIM + by + x] = tile[x][y + i];
}

// ========== tri-GEMM (r13 base, 32x32x16 MFMA): 256x128, 8 waves ==========
// H = bf16(relu(x@W1+b1)); G = bf16(sigmoid(x@Wg+bg)); S = bf16(x@Ws+bs)
// Wave = 128 rows x 32 cols per weight (2x4 split).  32x32x16 MFMA:
// same LDS bytes (14 b128 reads/wave/tile, bank-uniform with the proven
// swizzle) but HALF the MFMA instructions (24 vs 48) at the higher-ceiling
// shape.  Operand map: lane holds row/col lane&31, k-group 8*(lane>>5);
// C/D: col=lane&31, row=(reg&3)+8*(reg>>2)+4*(lane>>5)  [m74/m101].
// r13's validated single-barrier counted loop; LDS 80 KB.
__global__ __launch_bounds__(512, 2) void trigemm(
    const unsigned short* __restrict__ A,
    const unsigned short* __restrict__ W1t,
    const unsigned short* __restrict__ Wgt,
    const unsigned short* __restrict__ Wst,
    const float* __restrict__ b1,
    const float* __restrict__ bg,
    const float* __restrict__ bs,
    unsigned short* __restrict__ H,
    unsigned short* __restrict__ G,
    unsigned short* __restrict__ S) {
  // per buf: shorts 0..8191 = A (row-major 256x32), 8192 + w*4096 + row*32 = W_w
  __shared__ __align__(16) unsigned short lds[2][20480];  // 80 KB

  const int tid = threadIdx.x;
  const int lane = tid & 63;
  const int wave = tid >> 6;            // 0..7
  const int wm = wave >> 2;             // 0..1  (128-row band)
  const int wn = wave & 3;              // 0..3  (32-col slice)
  const int lr32 = lane & 31;
  const int lkh = lane >> 5;            // k-group half (0/1)

  // XCD swizzle: 8 col-blocks sharing an A row-panel -> same XCD.
  const int id = blockIdx.x;
  const int xcd = id & 7;
  const int slot = id >> 3;                // 0..63
  const int rblk = xcd + 8 * (slot >> 3);  // 0..63
  const int cblk = slot & 7;               // 0..7
  const int m0 = rblk * 256, n0 = cblk * 128;

  const unsigned short* gA = A + (size_t)m0 * NDIM;
  const unsigned short* gW[3] = {W1t + (size_t)n0 * NDIM, Wgt + (size_t)n0 * NDIM,
                                 Wst + (size_t)n0 * NDIM};

  f32x16 acc[3][4] = {};

  // stage K-tile kt: A 1024 chunks + 3x512 W chunks = 2560 / 512thr = 5 each
  auto stage = [&](int buf, int kt) {
#pragma unroll
    for (int q = 0; q < 5; ++q) {
      int cid = q * 512 + tid;             // 0..2559
      const unsigned short* g;
      if (q < 2) {                          // A chunks 0..1023
        int row = cid >> 2;                 // 0..255
        int c = (cid & 3) ^ ((row >> 1) & 3);
        g = gA + (size_t)row * NDIM + kt * BK + c * 8;
      } else {                              // W chunks, w = q-2 (compile-time)
        int local = cid - 1024;
        int w = q - 2;
        int lrow = local & 511;
        int row = lrow >> 2;                // 0..127
        int c = (lrow & 3) ^ ((row >> 1) & 3);
        g = gW[w] + (size_t)row * NDIM + kt * BK + c * 8;
      }
      unsigned short* l = &lds[buf][0] + (size_t)(q * 512 + (tid & ~63)) * 8;
      __builtin_amdgcn_global_load_lds(
          (__attribute__((address_space(1))) void*)g,
          (__attribute__((address_space(3))) void*)l, 16, 0, 0);
    }
  };

  auto compute = [&](int buf) {
    short8 af[8];   // [mi*2+ks]: A row-tile mi, k-step ks
#pragma unroll
    for (int mi = 0; mi < 4; ++mi)
#pragma unroll
      for (int ks = 0; ks < 2; ++ks) {
        int row = wm * 128 + mi * 32 + lr32;
        int cs = (ks * 2 + lkh) ^ ((row >> 1) & 3);
        af[mi * 2 + ks] =
            *reinterpret_cast<const short8*>(&lds[buf][row * 32 + cs * 8]);
      }
#pragma unroll
    for (int w = 0; w < 3; ++w) {
      short8 bf[2];
#pragma unroll
      for (int ks = 0; ks < 2; ++ks) {
        int row = wn * 32 + lr32;
        int cs = (ks * 2 + lkh) ^ ((row >> 1) & 3);
        bf[ks] = *reinterpret_cast<const short8*>(
            &lds[buf][8192 + w * 4096 + row * 32 + cs * 8]);
      }
      __builtin_amdgcn_s_setprio(1);
#pragma unroll
      for (int mi = 0; mi < 4; ++mi)
#pragma unroll
        for (int ks = 0; ks < 2; ++ks)
          acc[w][mi] = __builtin_amdgcn_mfma_f32_32x32x16_bf16(
              af[mi * 2 + ks], bf[ks], acc[w][mi], 0, 0, 0);
      __builtin_amdgcn_s_setprio(0);
    }
  };

  // prologue: tile 0 staged and landed
  stage(0, 0);
  VMW(0);
  BAR();
  for (int t = 0; t < NT; ++t) {
    const int cur = t & 1;
    if (t + 1 < NT) stage(cur ^ 1, t + 1);  // issue early, land under compute
    compute(cur);
    VMW(0);                                 // own next-tile loads landed
    BAR();                                  // single barrier per tile
  }

  // epilogue: 32x32 C/D: col=lane&31, row=(r&3)+8*(r>>2)+4*lkh
  const int ccol = n0 + wn * 32 + lr32;
#pragma unroll
  for (int w = 0; w < 3; ++w) {
    const float* bptr = (w == 0) ? b1 : (w == 1) ? bg : bs;
    unsigned short* optr = (w == 0) ? H : (w == 1) ? G : S;
    float bc = bptr[ccol];
#pragma unroll
    for (int mi = 0; mi < 4; ++mi) {
      int rbase = m0 + wm * 128 + mi * 32 + 4 * lkh;
#pragma unroll
      for (int r = 0; r < 16; ++r) {
        int row = rbase + (r & 3) + 8 * (r >> 2);
        float v = acc[w][mi][r] + bc;
        if (w == 0) v = fmaxf(v, 0.f);
        else if (w == 1) v = 1.f / (1.f + __expf(-v));
        optr[(size_t)row * NDIM + ccol] = f2bf(v);
      }
    }
  }
}

// ========== y-GEMM (r13 base, 32x32x16 MFMA): 256x128, 8 waves ==========
// O = bf16((H@W2t^T + b2) * G + S)
__global__ __launch_bounds__(512, 2) void gemm_y(
    const unsigned short* __restrict__ A,
    const unsigned short* __restrict__ Bt,
    const float* __restrict__ bias,
    unsigned short* __restrict__ O,
    const unsigned short* __restrict__ G,
    const unsigned short* __restrict__ S) {
  // per buf: shorts 0..8191 = A (256x32), 8192 + row*32 = B (128x32)
  __shared__ __align__(16) unsigned short lds[2][12288];  // 48 KB

  const int tid = threadIdx.x;
  const int lane = tid & 63;
  const int wave = tid >> 6;            // 0..7
  const int wm = wave >> 2;             // 0..1  (128-row band)
  const int wn = wave & 3;              // 0..3  (32-col slice)
  const int lr32 = lane & 31;
  const int lkh = lane >> 5;

  // XCD swizzle: 8 col-blocks per A row-panel -> same XCD (512 blocks)
  const int id = blockIdx.x;
  const int xcd = id & 7;
  const int slot = id >> 3;                // 0..63
  const int rblk = xcd + 8 * (slot >> 3);  // 0..63
  const int cblk = slot & 7;               // 0..7
  const int m0 = rblk * 256, n0 = cblk * 128;

  const unsigned short* gA = A + (size_t)m0 * NDIM;
  const unsigned short* gB = Bt + (size_t)n0 * NDIM;

  f32x16 acc[4] = {};

  // stage K-tile kt: A 1024 + B 512 chunks = 1536 / 512thr = 3 each
  auto stage = [&](int buf, int kt) {
#pragma unroll
    for (int q = 0; q < 3; ++q) {
      int cid = q * 512 + tid;             // 0..1535
      const unsigned short* g;
      if (q < 2) {                          // A chunks 0..1023
        int row = cid >> 2;                 // 0..255
        int c = (cid & 3) ^ ((row >> 1) & 3);
        g = gA + (size_t)row * NDIM + kt * BK + c * 8;
      } else {                              // B chunks 0..511
        int local = cid - 1024;
        int row = local >> 2;               // 0..127
        int c = (local & 3) ^ ((row >> 1) & 3);
        g = gB + (size_t)row * NDIM + kt * BK + c * 8;
      }
      unsigned short* l = &lds[buf][0] + (size_t)(q * 512 + (tid & ~63)) * 8;
      __builtin_amdgcn_global_load_lds(
          (__attribute__((address_space(1))) void*)g,
          (__attribute__((address_space(3))) void*)l, 16, 0, 0);
    }
  };

  auto compute = [&](int buf) {
    short8 af[8], bf[2];
#pragma unroll
    for (int mi = 0; mi < 4; ++mi)
#pragma unroll
      for (int ks = 0; ks < 2; ++ks) {
        int row = wm * 128 + mi * 32 + lr32;
        int cs = (ks * 2 + lkh) ^ ((row >> 1) & 3);
        af[mi * 2 + ks] =
            *reinterpret_cast<const short8*>(&lds[buf][row * 32 + cs * 8]);
      }
#pragma unroll
    for (int ks = 0; ks < 2; ++ks) {
      int row = wn * 32 + lr32;
      int cs = (ks * 2 + lkh) ^ ((row >> 1) & 3);
      bf[ks] = *reinterpret_cast<const short8*>(
          &lds[buf][8192 + row * 32 + cs * 8]);
    }
    __builtin_amdgcn_s_setprio(1);
#pragma unroll
    for (int mi = 0; mi < 4; ++mi)
#pragma unroll
      for (int ks = 0; ks < 2; ++ks)
        acc[mi] = __builtin_amdgcn_mfma_f32_32x32x16_bf16(
            af[mi * 2 + ks], bf[ks], acc[mi], 0, 0, 0);
    __builtin_amdgcn_s_setprio(0);
  };

  stage(0, 0);
  VMW(0);
  BAR();
  for (int t = 0; t < NT; ++t) {
    const int cur = t & 1;
    if (t + 1 < NT) stage(cur ^ 1, t + 1);
    compute(cur);
    VMW(0);
    BAR();
  }

  // epilogue: gate + skip, write bf16 Ybf
  const int ccol = n0 + wn * 32 + lr32;
  float bc = bias[ccol];
#pragma unroll
  for (int mi = 0; mi < 4; ++mi) {
    int rbase = m0 + wm * 128 + mi * 32 + 4 * lkh;
#pragma unroll
    for (int r = 0; r < 16; ++r) {
      int row = rbase + (r & 3) + 8 * (r >> 2);
      size_t idx = (size_t)row * NDIM + ccol;
      float v = acc[mi][r] + bc;
      O[idx] = f2bf(v * bf2f(G[idx]) + bf2f(S[idx]));
    }
  }
}

// -------- LayerNorm: bf16 rows in, fp32 out (proven r5) --------
__global__ __launch_bounds__(256) void layernorm_bf(
    const unsigned short* __restrict__ Ybf, float* __restrict__ Out,
    const float* __restrict__ gamma, const float* __restrict__ beta) {
  const int tid = threadIdx.x;
  const unsigned short* y = Ybf + (size_t)blockIdx.x * NDIM;
  ushort4 u = reinterpret_cast<const ushort4*>(y)[tid];
  float v0 = bf2f(u.x), v1 = bf2f(u.y), v2 = bf2f(u.z), v3 = bf2f(u.w);
  float s1 = v0 + v1 + v2 + v3;
  float s2 = v0 * v0 + v1 * v1 + v2 * v2 + v3 * v3;
#pragma unroll
  for (int o = 32; o > 0; o >>= 1) {
    s1 += __shfl_down(s1, o, 64);
    s2 += __shfl_down(s2, o, 64);
  }
  __shared__ float red[8];
  int wave = tid >> 6, lane = tid & 63;
  if (lane == 0) { red[wave] = s1; red[wave + 4] = s2; }
  __syncthreads();
  float S1 = red[0] + red[1] + red[2] + red[3];
  float S2 = red[4] + red[5] + red[6] + red[7];
  float mu = S1 * (1.f / NDIM);
  float var = S2 * (1.f / NDIM) - mu * mu;
  float inv = rsqrtf(var + 1e-3f);
  float4 gm = reinterpret_cast<const float4*>(gamma)[tid];
  float4 bt = reinterpret_cast<const float4*>(beta)[tid];
  float4 o;
  o.x = (v0 - mu) * inv * gm.x + bt.x;
  o.y = (v1 - mu) * inv * gm.y + bt.y;
  o.z = (v2 - mu) * inv * gm.z + bt.z;
  o.w = (v3 - mu) * inv * gm.w + bt.w;
  reinterpret_cast<float4*>(Out + (size_t)blockIdx.x * NDIM)[tid] = o;
}

extern "C" void kernel_launch(void* const* d_in, const int* in_sizes, int n_in,
                              void* d_out, int out_size, void* d_ws, size_t ws_size,
                              hipStream_t stream) {
  const float* inp = (const float*)d_in[0];
  const float* w1 = (const float*)d_in[1];
  const float* b1 = (const float*)d_in[2];
  const float* w2 = (const float*)d_in[3];
  const float* b2 = (const float*)d_in[4];
  const float* wg = (const float*)d_in[5];
  const float* bg = (const float*)d_in[6];
  const float* wsk = (const float*)d_in[7];
  const float* bs = (const float*)d_in[8];
  const float* gamma = (const float*)d_in[9];
  const float* beta = (const float*)d_in[10];

  char* p = (char*)d_ws;
  const size_t act_bf16 = (size_t)M_TOT * NDIM * 2;
  const size_t w_bf16 = (size_t)NDIM * NDIM * 2;
  unsigned short* Ain = (unsigned short*)p; p += act_bf16;
  unsigned short* H   = (unsigned short*)p; p += act_bf16;
  unsigned short* G   = (unsigned short*)p; p += act_bf16;
  unsigned short* S   = (unsigned short*)p; p += act_bf16;
  unsigned short* Ybf = (unsigned short*)p; p += act_bf16;
  unsigned short* W1t = (unsigned short*)p; p += w_bf16;
  unsigned short* W2t = (unsigned short*)p; p += w_bf16;
  unsigned short* Wgt = (unsigned short*)p; p += w_bf16;
  unsigned short* Wst = (unsigned short*)p; p += w_bf16;

  cast_in<<<(M_TOT * NDIM / 4 + 255) / 256, 256, 0, stream>>>(inp, Ain, M_TOT * NDIM / 4);
  tcast4<<<dim3(32, 32, 4), 256, 0, stream>>>(w1, w2, wg, wsk, W1t, W2t, Wgt, Wst);

  trigemm<<<(M_TOT / 256) * (NDIM / 128), 512, 0, stream>>>(
      Ain, W1t, Wgt, Wst, b1, bg, bs, H, G, S);
  gemm_y<<<(M_TOT / 256) * (NDIM / 128), 512, 0, stream>>>(H, W2t, b2, Ybf, G, S);
  layernorm_bf<<<M_TOT, 256, 0, stream>>>(Ybf, (float*)d_out, gamma, beta);
}

// Round 17
// 188.628 us; speedup vs baseline: 1.0813x; 1.0813x over previous
//
#include <hip/hip_runtime.h>
#include <hip/hip_bf16.h>

typedef short short8 __attribute__((ext_vector_type(8)));
typedef float f32x4 __attribute__((ext_vector_type(4)));

#define M_TOT 16384   // B*S = 4*4096
#define NDIM  1024    // D = U = 1024
#define BK 32
#define NT (NDIM / BK)   // 32 K-tiles

static __device__ __forceinline__ unsigned short f2bf(float f) {
  unsigned int u = __builtin_bit_cast(unsigned int, f);
  unsigned int r = (u + 0x7fffu + ((u >> 16) & 1u)) >> 16;   // RN-even
  return (unsigned short)r;
}
static __device__ __forceinline__ float bf2f(unsigned short u) {
  return __builtin_bit_cast(float, ((unsigned int)u) << 16);
}

// compile-time-only reorder fence (zero runtime cost)
#define CLB() asm volatile("" ::: "memory")
#define VMW(N) asm volatile("s_waitcnt vmcnt(" #N ")" ::: "memory")
#define BAR() do { CLB(); __builtin_amdgcn_s_barrier(); CLB(); } while (0)

// ---------------- cast inputs fp32 -> bf16, vectorized ----------------
__global__ __launch_bounds__(256) void cast_in(const float* __restrict__ in,
                                               unsigned short* __restrict__ out,
                                               int n4) {
  int i = blockIdx.x * 256 + threadIdx.x;
  if (i >= n4) return;
  float4 v = reinterpret_cast<const float4*>(in)[i];
  ushort4 o;
  o.x = f2bf(v.x); o.y = f2bf(v.y); o.z = f2bf(v.z); o.w = f2bf(v.w);
  reinterpret_cast<ushort4*>(out)[i] = o;
}

// ---- transpose-cast 4 weights fp32 [K][N] -> bf16 [N][K], one launch ----
__global__ __launch_bounds__(256) void tcast4(
    const float* __restrict__ w1, const float* __restrict__ w2,
    const float* __restrict__ wg, const float* __restrict__ ws,
    unsigned short* __restrict__ W1t, unsigned short* __restrict__ W2t,
    unsigned short* __restrict__ Wgt, unsigned short* __restrict__ Wst) {
  const int z = blockIdx.z;
  const float* src = (z == 0) ? w1 : (z == 1) ? w2 : (z == 2) ? wg : ws;
  unsigned short* dst = (z == 0) ? W1t : (z == 1) ? W2t : (z == 2) ? Wgt : Wst;
  __shared__ unsigned short tile[32][33];
  int bx = blockIdx.x * 32, by = blockIdx.y * 32;
  int x = threadIdx.x & 31, y = threadIdx.x >> 5;  // 32 x 8
#pragma unroll
  for (int i = 0; i < 32; i += 8)
    tile[y + i][x] = f2bf(src[(size_t)(by + y + i) * NDIM + bx + x]);
  __syncthreads();
#pragma unroll
  for (int i = 0; i < 32; i += 8)
    dst[(size_t)(bx + y + i) * NDIM + by + x] = tile[x][y + i];
}

// ========== tri-GEMM (r13 best): 256x128 tile, 8 waves (2x4) ==========
// H = bf16(relu(x@W1+b1)); G = bf16(sigmoid(x@Wg+bg)); S = bf16(x@Ws+bs)
// Wave = 128 rows x 32 cols per weight; LDS reads/wave/tile = A 8 + B 6
// b128 (B is the 3x-replicated operand, so narrow per-wave B-cols).
// Single barrier per K-tile: stage(next) -> compute(cur) -> vmcnt(0) -> bar.
// Measured (r13): 135 us profiled, MfmaUtil 33%, conflicts 0, FETCH 66 MB.
__global__ __launch_bounds__(512, 2) void trigemm(
    const unsigned short* __restrict__ A,
    const unsigned short* __restrict__ W1t,
    const unsigned short* __restrict__ Wgt,
    const unsigned short* __restrict__ Wst,
    const float* __restrict__ b1,
    const float* __restrict__ bg,
    const float* __restrict__ bs,
    unsigned short* __restrict__ H,
    unsigned short* __restrict__ G,
    unsigned short* __restrict__ S) {
  // per buf: shorts 0..8191 = A (row-major 256x32), 8192 + w*4096 + row*32 = W_w
  __shared__ __align__(16) unsigned short lds[2][20480];  // 80 KB

  const int tid = threadIdx.x;
  const int lane = tid & 63;
  const int wave = tid >> 6;            // 0..7
  const int wm = wave >> 2;             // 0..1  (128-row band)
  const int wn = wave & 3;              // 0..3  (32-col slice)
  const int lr = lane & 15;
  const int lk = lane >> 4;

  // XCD swizzle: 8 col-blocks sharing an A row-panel -> same XCD.
  const int id = blockIdx.x;
  const int xcd = id & 7;
  const int slot = id >> 3;                // 0..63
  const int rblk = xcd + 8 * (slot >> 3);  // 0..63
  const int cblk = slot & 7;               // 0..7
  const int m0 = rblk * 256, n0 = cblk * 128;

  const unsigned short* gA = A + (size_t)m0 * NDIM;
  const unsigned short* gW[3] = {W1t + (size_t)n0 * NDIM, Wgt + (size_t)n0 * NDIM,
                                 Wst + (size_t)n0 * NDIM};

  f32x4 acc[3][8][2] = {};

  // stage K-tile kt: A 1024 chunks + 3x512 W chunks = 2560 / 512thr = 5 each
  auto stage = [&](int buf, int kt) {
#pragma unroll
    for (int q = 0; q < 5; ++q) {
      int cid = q * 512 + tid;             // 0..2559
      const unsigned short* g;
      if (q < 2) {                          // A chunks 0..1023
        int row = cid >> 2;                 // 0..255
        int c = (cid & 3) ^ ((row >> 1) & 3);
        g = gA + (size_t)row * NDIM + kt * BK + c * 8;
      } else {                              // W chunks, mat = q-2 (compile-time)
        int local = cid - 1024;
        int w = q - 2;
        int lrow = local & 511;
        int row = lrow >> 2;                // 0..127
        int c = (lrow & 3) ^ ((row >> 1) & 3);
        g = gW[w] + (size_t)row * NDIM + kt * BK + c * 8;
      }
      unsigned short* l = &lds[buf][0] + (size_t)(q * 512 + (tid & ~63)) * 8;
      __builtin_amdgcn_global_load_lds(
          (__attribute__((address_space(1))) void*)g,
          (__attribute__((address_space(3))) void*)l, 16, 0, 0);
    }
  };

  auto compute = [&](int buf) {
    short8 af[8];
#pragma unroll
    for (int mi = 0; mi < 8; ++mi) {
      int row = wm * 128 + mi * 16 + lr;
      int cs = lk ^ ((row >> 1) & 3);
      af[mi] = *reinterpret_cast<const short8*>(&lds[buf][row * 32 + cs * 8]);
    }
#pragma unroll
    for (int w = 0; w < 3; ++w) {
      short8 bf[2];
#pragma unroll
      for (int nj = 0; nj < 2; ++nj) {
        int row = wn * 32 + nj * 16 + lr;
        int cs = lk ^ ((row >> 1) & 3);
        bf[nj] = *reinterpret_cast<const short8*>(
            &lds[buf][8192 + w * 4096 + row * 32 + cs * 8]);
      }
      __builtin_amdgcn_s_setprio(1);
#pragma unroll
      for (int mi = 0; mi < 8; ++mi)
#pragma unroll
        for (int nj = 0; nj < 2; ++nj)
          acc[w][mi][nj] = __builtin_amdgcn_mfma_f32_16x16x32_bf16(
              af[mi], bf[nj], acc[w][mi][nj], 0, 0, 0);
      __builtin_amdgcn_s_setprio(0);
    }
  };

  // prologue: tile 0 staged and landed
  stage(0, 0);
  VMW(0);
  BAR();
  for (int t = 0; t < NT; ++t) {
    const int cur = t & 1;
    if (t + 1 < NT) stage(cur ^ 1, t + 1);  // issue early, land under compute
    compute(cur);
    VMW(0);                                 // own next-tile loads landed
    BAR();                                  // single barrier per tile
  }

  // epilogue: C/D layout col = lane&15, row = (lane>>4)*4 + r
  const int crow0 = m0 + wm * 128;
  const int ccol0 = n0 + wn * 32;
#pragma unroll
  for (int w = 0; w < 3; ++w) {
    const float* bptr = (w == 0) ? b1 : (w == 1) ? bg : bs;
    unsigned short* optr = (w == 0) ? H : (w == 1) ? G : S;
#pragma unroll
    for (int mi = 0; mi < 8; ++mi) {
#pragma unroll
      for (int nj = 0; nj < 2; ++nj) {
        int row = crow0 + mi * 16 + (lk << 2);
        int col = ccol0 + nj * 16 + lr;
        float bc = bptr[col];
#pragma unroll
        for (int r = 0; r < 4; ++r) {
          float v = acc[w][mi][nj][r] + bc;
          if (w == 0) v = fmaxf(v, 0.f);
          else if (w == 1) v = 1.f / (1.f + __expf(-v));
          optr[(size_t)(row + r) * NDIM + col] = f2bf(v);
        }
      }
    }
  }
}

// ========== y-GEMM (r13 best): 256x128 tile, 8 waves (2x4), 48 KB ==========
// O = bf16((H@W2t^T + b2) * G + S)
__global__ __launch_bounds__(512, 2) void gemm_y(
    const unsigned short* __restrict__ A,
    const unsigned short* __restrict__ Bt,
    const float* __restrict__ bias,
    unsigned short* __restrict__ O,
    const unsigned short* __restrict__ G,
    const unsigned short* __restrict__ S) {
  // per buf: shorts 0..8191 = A (256x32), 8192 + row*32 = B (128x32)
  __shared__ __align__(16) unsigned short lds[2][12288];  // 48 KB

  const int tid = threadIdx.x;
  const int lane = tid & 63;
  const int wave = tid >> 6;            // 0..7
  const int wm = wave >> 2;             // 0..1  (128-row band)
  const int wn = wave & 3;              // 0..3  (32-col slice)
  const int lr = lane & 15;
  const int lk = lane >> 4;

  // XCD swizzle: 8 col-blocks per A row-panel -> same XCD (512 blocks)
  const int id = blockIdx.x;
  const int xcd = id & 7;
  const int slot = id >> 3;                // 0..63
  const int rblk = xcd + 8 * (slot >> 3);  // 0..63
  const int cblk = slot & 7;               // 0..7
  const int m0 = rblk * 256, n0 = cblk * 128;

  const unsigned short* gA = A + (size_t)m0 * NDIM;
  const unsigned short* gB = Bt + (size_t)n0 * NDIM;

  f32x4 acc[8][2] = {};

  // stage K-tile kt: A 1024 + B 512 chunks = 1536 / 512thr = 3 each
  auto stage = [&](int buf, int kt) {
#pragma unroll
    for (int q = 0; q < 3; ++q) {
      int cid = q * 512 + tid;             // 0..1535
      const unsigned short* g;
      if (q < 2) {                          // A chunks 0..1023
        int row = cid >> 2;                 // 0..255
        int c = (cid & 3) ^ ((row >> 1) & 3);
        g = gA + (size_t)row * NDIM + kt * BK + c * 8;
      } else {                              // B chunks 0..511
        int local = cid - 1024;
        int row = local >> 2;               // 0..127
        int c = (local & 3) ^ ((row >> 1) & 3);
        g = gB + (size_t)row * NDIM + kt * BK + c * 8;
      }
      unsigned short* l = &lds[buf][0] + (size_t)(q * 512 + (tid & ~63)) * 8;
      __builtin_amdgcn_global_load_lds(
          (__attribute__((address_space(1))) void*)g,
          (__attribute__((address_space(3))) void*)l, 16, 0, 0);
    }
  };

  auto compute = [&](int buf) {
    short8 af[8], bf[2];
#pragma unroll
    for (int mi = 0; mi < 8; ++mi) {
      int row = wm * 128 + mi * 16 + lr;
      int cs = lk ^ ((row >> 1) & 3);
      af[mi] = *reinterpret_cast<const short8*>(&lds[buf][row * 32 + cs * 8]);
    }
#pragma unroll
    for (int nj = 0; nj < 2; ++nj) {
      int row = wn * 32 + nj * 16 + lr;
      int cs = lk ^ ((row >> 1) & 3);
      bf[nj] = *reinterpret_cast<const short8*>(&lds[buf][8192 + row * 32 + cs * 8]);
    }
    __builtin_amdgcn_s_setprio(1);
#pragma unroll
    for (int mi = 0; mi < 8; ++mi)
#pragma unroll
      for (int nj = 0; nj < 2; ++nj)
        acc[mi][nj] = __builtin_amdgcn_mfma_f32_16x16x32_bf16(
            af[mi], bf[nj], acc[mi][nj], 0, 0, 0);
    __builtin_amdgcn_s_setprio(0);
  };

  stage(0, 0);
  VMW(0);
  BAR();
  for (int t = 0; t < NT; ++t) {
    const int cur = t & 1;
    if (t + 1 < NT) stage(cur ^ 1, t + 1);
    compute(cur);
    VMW(0);
    BAR();
  }

  // epilogue: gate + skip, write bf16 Ybf
  const int crow0 = m0 + wm * 128;
  const int ccol0 = n0 + wn * 32;
#pragma unroll
  for (int mi = 0; mi < 8; ++mi) {
#pragma unroll
    for (int nj = 0; nj < 2; ++nj) {
      int row = crow0 + mi * 16 + (lk << 2);
      int col = ccol0 + nj * 16 + lr;
      float bc = bias[col];
#pragma unroll
      for (int r = 0; r < 4; ++r) {
        float v = acc[mi][nj][r] + bc;
        size_t idx = (size_t)(row + r) * NDIM + col;
        O[idx] = f2bf(v * bf2f(G[idx]) + bf2f(S[idx]));
      }
    }
  }
}

// -------- LayerNorm: bf16 rows in, fp32 out (proven r5) --------
__global__ __launch_bounds__(256) void layernorm_bf(
    const unsigned short* __restrict__ Ybf, float* __restrict__ Out,
    const float* __restrict__ gamma, const float* __restrict__ beta) {
  const int tid = threadIdx.x;
  const unsigned short* y = Ybf + (size_t)blockIdx.x * NDIM;
  ushort4 u = reinterpret_cast<const ushort4*>(y)[tid];
  float v0 = bf2f(u.x), v1 = bf2f(u.y), v2 = bf2f(u.z), v3 = bf2f(u.w);
  float s1 = v0 + v1 + v2 + v3;
  float s2 = v0 * v0 + v1 * v1 + v2 * v2 + v3 * v3;
#pragma unroll
  for (int o = 32; o > 0; o >>= 1) {
    s1 += __shfl_down(s1, o, 64);
    s2 += __shfl_down(s2, o, 64);
  }
  __shared__ float red[8];
  int wave = tid >> 6, lane = tid & 63;
  if (lane == 0) { red[wave] = s1; red[wave + 4] = s2; }
  __syncthreads();
  float S1 = red[0] + red[1] + red[2] + red[3];
  float S2 = red[4] + red[5] + red[6] + red[7];
  float mu = S1 * (1.f / NDIM);
  float var = S2 * (1.f / NDIM) - mu * mu;
  float inv = rsqrtf(var + 1e-3f);
  float4 gm = reinterpret_cast<const float4*>(gamma)[tid];
  float4 bt = reinterpret_cast<const float4*>(beta)[tid];
  float4 o;
  o.x = (v0 - mu) * inv * gm.x + bt.x;
  o.y = (v1 - mu) * inv * gm.y + bt.y;
  o.z = (v2 - mu) * inv * gm.z + bt.z;
  o.w = (v3 - mu) * inv * gm.w + bt.w;
  reinterpret_cast<float4*>(Out + (size_t)blockIdx.x * NDIM)[tid] = o;
}

extern "C" void kernel_launch(void* const* d_in, const int* in_sizes, int n_in,
                              void* d_out, int out_size, void* d_ws, size_t ws_size,
                              hipStream_t stream) {
  const float* inp = (const float*)d_in[0];
  const float* w1 = (const float*)d_in[1];
  const float* b1 = (const float*)d_in[2];
  const float* w2 = (const float*)d_in[3];
  const float* b2 = (const float*)d_in[4];
  const float* wg = (const float*)d_in[5];
  const float* bg = (const float*)d_in[6];
  const float* wsk = (const float*)d_in[7];
  const float* bs = (const float*)d_in[8];
  const float* gamma = (const float*)d_in[9];
  const float* beta = (const float*)d_in[10];

  char* p = (char*)d_ws;
  const size_t act_bf16 = (size_t)M_TOT * NDIM * 2;
  const size_t w_bf16 = (size_t)NDIM * NDIM * 2;
  unsigned short* Ain = (unsigned short*)p; p += act_bf16;
  unsigned short* H   = (unsigned short*)p; p += act_bf16;
  unsigned short* G   = (unsigned short*)p; p += act_bf16;
  unsigned short* S   = (unsigned short*)p; p += act_bf16;
  unsigned short* Ybf = (unsigned short*)p; p += act_bf16;
  unsigned short* W1t = (unsigned short*)p; p += w_bf16;
  unsigned short* W2t = (unsigned short*)p; p += w_bf16;
  unsigned short* Wgt = (unsigned short*)p; p += w_bf16;
  unsigned short* Wst = (unsigned short*)p; p += w_bf16;

  cast_in<<<(M_TOT * NDIM / 4 + 255) / 256, 256, 0, stream>>>(inp, Ain, M_TOT * NDIM / 4);
  tcast4<<<dim3(32, 32, 4), 256, 0, stream>>>(w1, w2, wg, wsk, W1t, W2t, Wgt, Wst);

  trigemm<<<(M_TOT / 256) * (NDIM / 128), 512, 0, stream>>>(
      Ain, W1t, Wgt, Wst, b1, bg, bs, H, G, S);
  gemm_y<<<(M_TOT / 256) * (NDIM / 128), 512, 0, stream>>>(H, W2t, b2, Ybf, G, S);
  layernorm_bf<<<M_TOT, 256, 0, stream>>>(Ybf, (float*)d_out, gamma, beta);
}